// Round 1
// baseline (1127.877 us; speedup 1.0000x reference)
//
#include <hip/hip_runtime.h>

#define AS1 __attribute__((address_space(1)))
#define AS3 __attribute__((address_space(3)))

typedef __attribute__((ext_vector_type(8))) short short8;
typedef __attribute__((ext_vector_type(4))) float f32x4;
typedef unsigned int u32;
typedef unsigned short u16;

static constexpr int NN = 20000;
static constexpr int NE = 320000;
static constexpr int INC = 2000;
static constexpr int KX = 2048;   // padded IN_C
static constexpr int HID = 512;
static constexpr int OUTC = 256;
static constexpr int QA = 100;
static constexpr int KQ = 128;    // padded Q
static constexpr long OUTSZ = (long)NN * OUTC;

__device__ __forceinline__ u16 f2bf(float f) {
  u32 u = __float_as_uint(f);
  u = (u + 0x7FFFu + ((u >> 16) & 1u)) >> 16;   // RNE
  return (u16)u;
}
__device__ __forceinline__ float bf2f(u16 h) {
  return __uint_as_float(((u32)h) << 16);
}
__device__ __forceinline__ void ld_bf16x8(const u16* p, float* f) {
  uint4 r = *(const uint4*)p;
  u32 a0 = r.x, a1 = r.y, a2 = r.z, a3 = r.w;
  f[0] = __uint_as_float(a0 << 16); f[1] = __uint_as_float(a0 & 0xFFFF0000u);
  f[2] = __uint_as_float(a1 << 16); f[3] = __uint_as_float(a1 & 0xFFFF0000u);
  f[4] = __uint_as_float(a2 << 16); f[5] = __uint_as_float(a2 & 0xFFFF0000u);
  f[6] = __uint_as_float(a3 << 16); f[7] = __uint_as_float(a3 & 0xFFFF0000u);
}
__device__ __forceinline__ void ld_bf16x4(const u16* p, float* f) {
  uint2 r = *(const uint2*)p;
  f[0] = __uint_as_float(r.x << 16); f[1] = __uint_as_float(r.x & 0xFFFF0000u);
  f[2] = __uint_as_float(r.y << 16); f[3] = __uint_as_float(r.y & 0xFFFF0000u);
}

// ---------------- casts ----------------

// f32 [M,Kin] -> bf16 [M,Kout] zero-padded (Kin%... handled scalar at tail)
__global__ void k_cast_pad(const float* __restrict__ x, u16* __restrict__ o,
                           int M, int Kin, int Kout) {
  long id = (long)blockIdx.x * blockDim.x + threadIdx.x;
  int kg = Kout >> 3;
  long tot = (long)M * kg;
  if (id >= tot) return;
  int row = (int)(id / kg);
  int c8 = (int)(id % kg) << 3;
  u16 v[8];
  if (c8 + 8 <= Kin) {
    const float4* p = (const float4*)(x + (long)row * Kin + c8);
    float4 a = p[0], b = p[1];
    v[0] = f2bf(a.x); v[1] = f2bf(a.y); v[2] = f2bf(a.z); v[3] = f2bf(a.w);
    v[4] = f2bf(b.x); v[5] = f2bf(b.y); v[6] = f2bf(b.z); v[7] = f2bf(b.w);
  } else {
#pragma unroll
    for (int j = 0; j < 8; j++) {
      int c = c8 + j;
      v[j] = (c < Kin) ? f2bf(x[(long)row * Kin + c]) : (u16)0;
    }
  }
  *(uint4*)(o + (long)row * Kout + c8) = *(const uint4*)v;
}

// W_rna1|W_rna2 [2000,512] each -> WcT bf16 [1024, 2048] (transposed, zero-padded K)
__global__ void k_cast_wcT(const float* __restrict__ W1, const float* __restrict__ W2,
                           u16* __restrict__ o) {
  int id = blockIdx.x * blockDim.x + threadIdx.x;
  const int KG = KX >> 3;
  if (id >= 1024 * KG) return;
  int n = id / KG;
  int k8 = (id % KG) << 3;
  const float* W = (n < HID) ? W1 : W2;
  int nn = n & (HID - 1);
  u16 v[8];
#pragma unroll
  for (int j = 0; j < 8; j++) {
    int k = k8 + j;
    v[j] = (k < INC) ? f2bf(W[(long)k * HID + nn]) : (u16)0;
  }
  *(uint4*)(o + (long)n * KX + k8) = *(const uint4*)v;
}

// generic W [Kin,Nw] f32 -> WT bf16 [Nw, Kpad]
__global__ void k_cast_wT(const float* __restrict__ W, u16* __restrict__ o,
                          int Kin, int Nw, int Kpad) {
  int id = blockIdx.x * blockDim.x + threadIdx.x;
  int kg = Kpad >> 3;
  if (id >= Nw * kg) return;
  int n = id / kg;
  int k8 = (id % kg) << 3;
  u16 v[8];
#pragma unroll
  for (int j = 0; j < 8; j++) {
    int k = k8 + j;
    v[j] = (k < Kin) ? f2bf(W[(long)k * Nw + n]) : (u16)0;
  }
  *(uint4*)(o + (long)n * Kpad + k8) = *(const uint4*)v;
}

// ---------------- CSR build ----------------

__global__ void k_fill_f32(float* p, float v, int n) {
  int i = blockIdx.x * blockDim.x + threadIdx.x;
  if (i < n) p[i] = v;
}
__global__ void k_fill_i32(int* p, int v, int n) {
  int i = blockIdx.x * blockDim.x + threadIdx.x;
  if (i < n) p[i] = v;
}
__global__ void k_edge1(const int* __restrict__ ei, const float* __restrict__ ew,
                        float* deg, int* cnt, int E) {
  int e = blockIdx.x * blockDim.x + threadIdx.x;
  if (e >= E) return;
  int dst = ei[E + e];
  atomicAdd(&deg[dst], ew[e]);
  atomicAdd(&cnt[dst], 1);
}
__global__ void k_dinv(float* deg, int n) {
  int i = blockIdx.x * blockDim.x + threadIdx.x;
  if (i < n) deg[i] = rsqrtf(deg[i]);   // deg >= 1 always (self loop)
}
// exclusive prefix over cnt -> offs[0..n], single block of 256 threads
__global__ void k_scan(const int* __restrict__ cnt, int* __restrict__ offs, int n) {
  __shared__ int sums[256];
  const int C = 80;
  int t = threadIdx.x;
  int base = t * C;
  int s = 0;
  for (int i = 0; i < C; i++) {
    int idx = base + i;
    if (idx < n) s += cnt[idx];
  }
  sums[t] = s;
  __syncthreads();
  for (int off = 1; off < 256; off <<= 1) {
    int v = (t >= off) ? sums[t - off] : 0;
    __syncthreads();
    sums[t] += v;
    __syncthreads();
  }
  int run = (t == 0) ? 0 : sums[t - 1];
  for (int i = 0; i < C; i++) {
    int idx = base + i;
    if (idx <= n) offs[idx] = run;
    if (idx < n) run += cnt[idx];
  }
}
__global__ void k_fill_csr(const int* __restrict__ ei, const float* __restrict__ ew,
                           const float* __restrict__ dinv, const int* __restrict__ offs,
                           int* cur, int* csrc, float* cw, int E) {
  int e = blockIdx.x * blockDim.x + threadIdx.x;
  if (e >= E) return;
  int s = ei[e], d = ei[E + e];
  float w = ew[e];
  int pos = offs[d] + atomicAdd(&cur[d], 1);
  csrc[pos] = s;
  cw[pos] = dinv[s] * w * dinv[d];
}

// ---------------- GEMM (bf16 MFMA, 128x128 tile, BK=32) ----------------

__device__ __forceinline__ void gload_lds16(const void* g, void* l) {
  __builtin_amdgcn_global_load_lds((const AS1 void*)g, (AS3 void*)l, 16, 0, 0);
}

// A [M,lda] bf16 row-major; BT [N,ldb] bf16 (B transposed); K%32==0; N%128==0.
__global__ __launch_bounds__(256) void k_gemm(
    const u16* __restrict__ A, int lda, int M,
    const u16* __restrict__ BT, int ldb, int K,
    const float* __restrict__ bias,
    float* __restrict__ outF, int ldf,
    u16* __restrict__ outB, int ldob, int obOff) {
  __shared__ u16 lA[128 * 32];
  __shared__ u16 lB[128 * 32];
  const int tid = threadIdx.x;
  const int l = tid & 63;
  const int w = tid >> 6;
  const int wr = w >> 1, wc = w & 1;
  const int m0 = blockIdx.x * 128, n0 = blockIdx.y * 128;

  f32x4 acc[4][4];
  const f32x4 z = {0.f, 0.f, 0.f, 0.f};
#pragma unroll
  for (int i = 0; i < 4; i++)
#pragma unroll
    for (int j = 0; j < 4; j++) acc[i][j] = z;

  const u16* gA[2];
  const u16* gB[2];
  u16* lAq[2];
  u16* lBq[2];
#pragma unroll
  for (int q = 0; q < 2; q++) {
    int ch = w * 128 + q * 64 + l;       // chunk id 0..511
    int r = ch >> 2, kc = ch & 3;        // tile row, k-subchunk (8 elems)
    int ra = m0 + r; if (ra > M - 1) ra = M - 1;   // clamp M-tail
    gA[q] = A + (size_t)ra * lda + kc * 8;
    gB[q] = BT + (size_t)(n0 + r) * ldb + kc * 8;
    lAq[q] = lA + (size_t)(w * 128 + q * 64) * 8;  // wave-uniform base
    lBq[q] = lB + (size_t)(w * 128 + q * 64) * 8;
  }

  const int fr = l & 15, qd = l >> 4;

  for (int kt = 0; kt < K; kt += 32) {
    __syncthreads();
#pragma unroll
    for (int q = 0; q < 2; q++) {
      gload_lds16(gA[q] + kt, lAq[q]);
      gload_lds16(gB[q] + kt, lBq[q]);
    }
    __syncthreads();
    short8 af[4], bf[4];
#pragma unroll
    for (int t = 0; t < 4; t++) {
      af[t] = *(const short8*)(lA + (wr * 64 + t * 16 + fr) * 32 + qd * 8);
      bf[t] = *(const short8*)(lB + (wc * 64 + t * 16 + fr) * 32 + qd * 8);
    }
#pragma unroll
    for (int i = 0; i < 4; i++)
#pragma unroll
      for (int j = 0; j < 4; j++)
        acc[i][j] = __builtin_amdgcn_mfma_f32_16x16x32_bf16(af[i], bf[j], acc[i][j], 0, 0, 0);
  }

#pragma unroll
  for (int i = 0; i < 4; i++) {
#pragma unroll
    for (int r = 0; r < 4; r++) {
      int m = m0 + wr * 64 + i * 16 + qd * 4 + r;
      if (m < M) {
#pragma unroll
        for (int j = 0; j < 4; j++) {
          int n = n0 + wc * 64 + j * 16 + fr;
          float v = acc[i][j][r];
          if (bias) v += bias[n];
          if (outF) outF[(size_t)m * ldf + n] = v;
          if (outB) outB[(size_t)m * ldob + obOff + n] = f2bf(v);
        }
      }
    }
  }
}

// ---------------- aggregation (pull, wave per node) ----------------

template <int CPL>   // cols per lane: 8 (512 cols) or 4 (256 cols)
__global__ void k_agg(const u16* __restrict__ H, int ldh, int colOff,
                      const int* __restrict__ offs, const int* __restrict__ csrc,
                      const float* __restrict__ cw, const float* __restrict__ dinv,
                      const float* __restrict__ bias,
                      float* __restrict__ outF, int ldf,
                      u16* __restrict__ outB, int ldob, int obOff,
                      int n, int relu) {
  int wid = blockIdx.x * (blockDim.x >> 6) + (threadIdx.x >> 6);
  if (wid >= n) return;
  int l = threadIdx.x & 63;
  const u16* hbase = H + colOff + (size_t)l * CPL;
  float acc[CPL], f[CPL];
  float dv = dinv[wid];
  float sw = dv * dv;   // self-loop norm
  if (CPL == 8) ld_bf16x8(hbase + (size_t)wid * ldh, f);
  else          ld_bf16x4(hbase + (size_t)wid * ldh, f);
#pragma unroll
  for (int j = 0; j < CPL; j++) acc[j] = f[j] * sw;
  int e0 = offs[wid], e1 = offs[wid + 1];
  for (int e = e0; e < e1; e++) {
    int s = csrc[e];
    float wn = cw[e];
    if (CPL == 8) ld_bf16x8(hbase + (size_t)s * ldh, f);
    else          ld_bf16x4(hbase + (size_t)s * ldh, f);
#pragma unroll
    for (int j = 0; j < CPL; j++) acc[j] += f[j] * wn;
  }
  const float* bp = bias + l * CPL;
#pragma unroll
  for (int j = 0; j < CPL; j++) {
    float v = acc[j] + bp[j];
    if (relu) v = v > 0.f ? v : 0.f;
    acc[j] = v;
  }
  if (outF) {
    float* q = outF + (size_t)wid * ldf + l * CPL;
#pragma unroll
    for (int j = 0; j < CPL; j++) q[j] = acc[j];
  }
  if (outB) {
    u16* q = outB + (size_t)wid * ldob + obOff + l * CPL;
#pragma unroll
    for (int j = 0; j < CPL; j++) q[j] = f2bf(acc[j]);
  }
}

// ---------------- launch ----------------

extern "C" void kernel_launch(void* const* d_in, const int* in_sizes, int n_in,
                              void* d_out, int out_size, void* d_ws, size_t ws_size,
                              hipStream_t stream) {
  (void)in_sizes; (void)n_in; (void)out_size; (void)ws_size;
  const float* x_RNA = (const float*)d_in[0];
  const float* x_ADT = (const float*)d_in[1];
  const int* ei[3] = {(const int*)d_in[2], (const int*)d_in[4], (const int*)d_in[6]};
  const float* ew[3] = {(const float*)d_in[3], (const float*)d_in[5], (const float*)d_in[7]};
  const float* W_rna1 = (const float*)d_in[8];  const float* b_rna1 = (const float*)d_in[9];
  const float* W_rna2 = (const float*)d_in[10]; const float* b_rna2 = (const float*)d_in[11];
  const float* W_p3   = (const float*)d_in[12]; const float* b_p3   = (const float*)d_in[13];
  const float* W_sim  = (const float*)d_in[14]; const float* b_sim  = (const float*)d_in[15];
  const float* W_dist = (const float*)d_in[16]; const float* b_dist = (const float*)d_in[17];
  const float* W_f1   = (const float*)d_in[18]; const float* b_f1   = (const float*)d_in[19];
  const float* W_f2   = (const float*)d_in[20]; const float* b_f2   = (const float*)d_in[21];
  float* out = (float*)d_out;

  // ---- workspace layout (~101 MB) ----
  char* p = (char*)d_ws;
  auto alloc = [&](size_t bytes) {
    char* r = p;
    p += (bytes + 255) & ~(size_t)255;
    return r;
  };
  u16* WcT  = (u16*)alloc((size_t)1024 * KX * 2);
  u16* WsT  = (u16*)alloc((size_t)OUTC * HID * 2);
  u16* WdT  = (u16*)alloc((size_t)OUTC * HID * 2);
  u16* Wf1T = (u16*)alloc((size_t)OUTC * HID * 2);
  u16* Wf2T = (u16*)alloc((size_t)OUTC * HID * 2);
  u16* Wp3T = (u16*)alloc((size_t)OUTC * KQ * 2);
  u16* ADTb = (u16*)alloc((size_t)NN * KQ * 2);
  u16* H1   = (u16*)alloc((size_t)NN * 1024 * 2);  // later: H2s|H2d|H2p
  u16* B2   = (u16*)alloc((size_t)NN * 1024 * 2);  // XS|XD, later XSD|FP
  float* deg[3]; int* cnt[3]; int* offs[3]; int* cur[3]; int* csrc[3]; float* cwn[3];
  for (int g = 0; g < 3; g++) {
    deg[g]  = (float*)alloc(NN * 4);
    cnt[g]  = (int*)alloc(NN * 4);
    offs[g] = (int*)alloc((NN + 1) * 4);
    cur[g]  = (int*)alloc(NN * 4);
    csrc[g] = (int*)alloc((size_t)NE * 4);
    cwn[g]  = (float*)alloc((size_t)NE * 4);
  }

  // Xb (bf16 x_RNA, padded) lives in d_out: dead before any f32 output is written.
  u16* Xb = (u16*)d_out;
  u16* XS  = B2;                          // [NN,512] relu'd layer-1 sim
  u16* XD  = B2 + (size_t)NN * 512;       // [NN,512] relu'd layer-1 dist
  u16* XSD = B2;                          // [NN,512] = [x_sim | x_dist]
  u16* FP  = B2 + (size_t)NN * 512;       // [NN,512] = [fused | pro]
  u16* H2s = H1;
  u16* H2d = H1 + (size_t)NN * 256;
  u16* H2p = H1 + (size_t)NN * 512;

  const int T = 256;
  // casts
  k_cast_pad<<<(NN * (KX / 8) + T - 1) / T, T, 0, stream>>>(x_RNA, Xb, NN, INC, KX);
  k_cast_pad<<<(NN * (KQ / 8) + T - 1) / T, T, 0, stream>>>(x_ADT, ADTb, NN, QA, KQ);
  k_cast_wcT<<<(1024 * (KX / 8) + T - 1) / T, T, 0, stream>>>(W_rna1, W_rna2, WcT);
  k_cast_wT<<<(OUTC * (HID / 8) + T - 1) / T, T, 0, stream>>>(W_sim, WsT, HID, OUTC, HID);
  k_cast_wT<<<(OUTC * (HID / 8) + T - 1) / T, T, 0, stream>>>(W_dist, WdT, HID, OUTC, HID);
  k_cast_wT<<<(OUTC * (HID / 8) + T - 1) / T, T, 0, stream>>>(W_f1, Wf1T, HID, OUTC, HID);
  k_cast_wT<<<(OUTC * (HID / 8) + T - 1) / T, T, 0, stream>>>(W_f2, Wf2T, HID, OUTC, HID);
  k_cast_wT<<<(OUTC * (KQ / 8) + T - 1) / T, T, 0, stream>>>(W_p3, Wp3T, QA, OUTC, KQ);
  // CSR per graph
  for (int g = 0; g < 3; g++) {
    k_fill_f32<<<(NN + T - 1) / T, T, 0, stream>>>(deg[g], 1.0f, NN);
    k_fill_i32<<<(NN + T - 1) / T, T, 0, stream>>>(cnt[g], 0, NN);
    k_fill_i32<<<(NN + T - 1) / T, T, 0, stream>>>(cur[g], 0, NN);
    k_edge1<<<(NE + T - 1) / T, T, 0, stream>>>(ei[g], ew[g], deg[g], cnt[g], NE);
    k_dinv<<<(NN + T - 1) / T, T, 0, stream>>>(deg[g], NN);
    k_scan<<<1, 256, 0, stream>>>(cnt[g], offs[g], NN);
    k_fill_csr<<<(NE + T - 1) / T, T, 0, stream>>>(ei[g], ew[g], deg[g], offs[g], cur[g],
                                                   csrc[g], cwn[g], NE);
  }
  // G1: H1 = Xb @ [W_rna1|W_rna2]   (82 GFLOP)
  k_gemm<<<dim3(157, 8), 256, 0, stream>>>(Xb, KX, NN, WcT, KX, KX,
                                           nullptr, nullptr, 0, H1, 1024, 0);
  // A1: XS = relu(agg_sim(H1[:, :512]) + b_rna1), XD likewise on dist
  k_agg<8><<<NN / 4, 256, 0, stream>>>(H1, 1024, 0, offs[0], csrc[0], cwn[0], deg[0],
                                       b_rna1, nullptr, 0, XS, 512, 0, NN, 1);
  k_agg<8><<<NN / 4, 256, 0, stream>>>(H1, 1024, 512, offs[1], csrc[1], cwn[1], deg[1],
                                       b_rna2, nullptr, 0, XD, 512, 0, NN, 1);
  // G2: H2s = XS@W_sim, H2d = XD@W_dist, H2p = ADTb@W_p3
  k_gemm<<<dim3(157, 2), 256, 0, stream>>>(XS, 512, NN, WsT, 512, 512,
                                           nullptr, nullptr, 0, H2s, 256, 0);
  k_gemm<<<dim3(157, 2), 256, 0, stream>>>(XD, 512, NN, WdT, 512, 512,
                                           nullptr, nullptr, 0, H2d, 256, 0);
  k_gemm<<<dim3(157, 2), 256, 0, stream>>>(ADTb, KQ, NN, Wp3T, KQ, KQ,
                                           nullptr, nullptr, 0, H2p, 256, 0);
  // A2: x_sim, x_dist, pro (f32 to d_out + bf16 copies for fusion GEMMs)
  k_agg<4><<<NN / 4, 256, 0, stream>>>(H2s, 256, 0, offs[0], csrc[0], cwn[0], deg[0],
                                       b_sim, out, 256, XSD, 512, 0, NN, 0);
  k_agg<4><<<NN / 4, 256, 0, stream>>>(H2d, 256, 0, offs[1], csrc[1], cwn[1], deg[1],
                                       b_dist, out + OUTSZ, 256, XSD, 512, 256, NN, 0);
  k_agg<4><<<NN / 4, 256, 0, stream>>>(H2p, 256, 0, offs[2], csrc[2], cwn[2], deg[2],
                                       b_p3, out + 4 * OUTSZ, 256, FP, 512, 256, NN, 0);
  // G3: fused = XSD @ W_f1 + b_f1  (f32 out + bf16 into FP[:, :256])
  k_gemm<<<dim3(157, 2), 256, 0, stream>>>(XSD, 512, NN, Wf1T, 512, 512,
                                           b_f1, out + 2 * OUTSZ, 256, FP, 512, 0);
  // G4: fused_pro = FP @ W_f2 + b_f2
  k_gemm<<<dim3(157, 2), 256, 0, stream>>>(FP, 512, NN, Wf2T, 512, 512,
                                           b_f2, out + 3 * OUTSZ, 256, nullptr, 0, 0);
}

// Round 2
// 862.559 us; speedup vs baseline: 1.3076x; 1.3076x over previous
//
#include <hip/hip_runtime.h>

#define AS1 __attribute__((address_space(1)))
#define AS3 __attribute__((address_space(3)))

typedef __attribute__((ext_vector_type(8))) short short8;
typedef __attribute__((ext_vector_type(4))) float f32x4;
typedef unsigned int u32;
typedef unsigned short u16;

static constexpr int NN = 20000;
static constexpr int NE = 320000;
static constexpr int INC = 2000;
static constexpr int KX = 2048;   // padded IN_C
static constexpr int HID = 512;
static constexpr int OUTC = 256;
static constexpr int QA = 100;
static constexpr int KQ = 128;    // padded Q
static constexpr long OUTSZ = (long)NN * OUTC;
static constexpr int NB79 = (NN + 255) / 256;   // 79

__device__ __forceinline__ u16 f2bf(float f) {
  u32 u = __float_as_uint(f);
  u = (u + 0x7FFFu + ((u >> 16) & 1u)) >> 16;   // RNE
  return (u16)u;
}
__device__ __forceinline__ void ld_bf16x8(const u16* p, float* f) {
  uint4 r = *(const uint4*)p;
  f[0] = __uint_as_float(r.x << 16); f[1] = __uint_as_float(r.x & 0xFFFF0000u);
  f[2] = __uint_as_float(r.y << 16); f[3] = __uint_as_float(r.y & 0xFFFF0000u);
  f[4] = __uint_as_float(r.z << 16); f[5] = __uint_as_float(r.z & 0xFFFF0000u);
  f[6] = __uint_as_float(r.w << 16); f[7] = __uint_as_float(r.w & 0xFFFF0000u);
}
__device__ __forceinline__ void ld_bf16x4(const u16* p, float* f) {
  uint2 r = *(const uint2*)p;
  f[0] = __uint_as_float(r.x << 16); f[1] = __uint_as_float(r.x & 0xFFFF0000u);
  f[2] = __uint_as_float(r.y << 16); f[3] = __uint_as_float(r.y & 0xFFFF0000u);
}

// ---------------- casts ----------------

__global__ void k_cast_pad(const float* __restrict__ x, u16* __restrict__ o,
                           int M, int Kin, int Kout) {
  long id = (long)blockIdx.x * blockDim.x + threadIdx.x;
  int kg = Kout >> 3;
  long tot = (long)M * kg;
  if (id >= tot) return;
  int row = (int)(id / kg);
  int c8 = (int)(id % kg) << 3;
  u16 v[8];
  if (c8 + 8 <= Kin) {
    const float4* p = (const float4*)(x + (long)row * Kin + c8);
    float4 a = p[0], b = p[1];
    v[0] = f2bf(a.x); v[1] = f2bf(a.y); v[2] = f2bf(a.z); v[3] = f2bf(a.w);
    v[4] = f2bf(b.x); v[5] = f2bf(b.y); v[6] = f2bf(b.z); v[7] = f2bf(b.w);
  } else {
#pragma unroll
    for (int j = 0; j < 8; j++) {
      int c = c8 + j;
      v[j] = (c < Kin) ? f2bf(x[(long)row * Kin + c]) : (u16)0;
    }
  }
  *(uint4*)(o + (long)row * Kout + c8) = *(const uint4*)v;
}

// WcT[n][k] = W(n)[k][n%512], LDS-tiled transpose. grid (32, 16), block 256.
__global__ void k_wcT(const float* __restrict__ W1, const float* __restrict__ W2,
                      u16* __restrict__ o) {
  __shared__ float tile[64][65];
  int kb = blockIdx.x * 64, nb = blockIdx.y * 64;
  int t = threadIdx.x;
  const float* W = (nb < HID) ? W1 : W2;
  int nb2 = nb & (HID - 1);
#pragma unroll
  for (int p = 0; p < 4; p++) {
    int idx = p * 256 + t;
    int r = idx >> 4, c4 = (idx & 15) << 2;
    int k = kb + r;
    float4 v = {0.f, 0.f, 0.f, 0.f};
    if (k < INC) v = *(const float4*)(W + (long)k * HID + nb2 + c4);
    tile[r][c4] = v.x; tile[r][c4 + 1] = v.y; tile[r][c4 + 2] = v.z; tile[r][c4 + 3] = v.w;
  }
  __syncthreads();
#pragma unroll
  for (int p = 0; p < 2; p++) {
    int idx = p * 256 + t;
    int n = idx >> 3, kg = (idx & 7) << 3;
    u16 v[8];
#pragma unroll
    for (int j = 0; j < 8; j++) v[j] = f2bf(tile[kg + j][n]);
    *(uint4*)(o + (long)(nb + n) * KX + kb + kg) = *(const uint4*)v;
  }
}

struct W5 {
  const float* W[5];
  u16* o[5];
  int Kin[5]; int Kpad[5]; int Nw[5];
};
// W [Kin,Nw] f32 -> WT bf16 [Nw, Kpad]; 5 jobs via blockIdx.y
__global__ void k_wT5(W5 js) {
  int g = blockIdx.y;
  int Kin = js.Kin[g], Kpad = js.Kpad[g], Nw = js.Nw[g];
  const float* W = js.W[g];
  u16* o = js.o[g];
  int id = blockIdx.x * blockDim.x + threadIdx.x;
  int kg = Kpad >> 3;
  if (id >= Nw * kg) return;
  int n = id / kg;
  int k8 = (id % kg) << 3;
  u16 v[8];
#pragma unroll
  for (int j = 0; j < 8; j++) {
    int k = k8 + j;
    v[j] = (k < Kin) ? f2bf(W[(long)k * Nw + n]) : (u16)0;
  }
  *(uint4*)(o + (long)n * Kpad + k8) = *(const uint4*)v;
}

// ---------------- CSR build ----------------

struct EJobs { const int* ei[3]; const float* ew[3]; };

__global__ void k_init_csr(float* deg, int* cnt, int* cur) {
  int i = blockIdx.x * blockDim.x + threadIdx.x;
  if (i < 3 * NN) { deg[i] = 1.0f; cnt[i] = 0; cur[i] = 0; }
}
__global__ void k_edge_count(EJobs js, float* deg, int* cnt) {
  int g = blockIdx.y;
  int e = blockIdx.x * blockDim.x + threadIdx.x;
  if (e >= NE) return;
  int dst = js.ei[g][NE + e];
  atomicAdd(&deg[g * NN + dst], js.ew[g][e]);
  atomicAdd(&cnt[g * NN + dst], 1);
}
__global__ void k_dinv(float* deg) {
  int i = blockIdx.x * blockDim.x + threadIdx.x;
  if (i < 3 * NN) deg[i] = rsqrtf(deg[i]);   // deg >= 1 (self loop)
}
// phase a: per-block sums. grid (NB79, 3)
__global__ void k_scan_a(const int* __restrict__ cnt, int* __restrict__ part) {
  __shared__ int buf[256];
  int g = blockIdx.y, b = blockIdx.x, t = threadIdx.x;
  int i = b * 256 + t;
  int v = (i < NN) ? cnt[g * NN + i] : 0;
  buf[t] = v;
  __syncthreads();
  for (int off = 128; off > 0; off >>= 1) {
    if (t < off) buf[t] += buf[t + off];
    __syncthreads();
  }
  if (t == 0) part[g * 128 + b] = buf[0];
}
// phase b: exclusive scan of 128 partials per graph, 1 block of 128
__global__ void k_scan_b(int* part) {
  __shared__ int buf[128];
  int t = threadIdx.x;
  for (int g = 0; g < 3; g++) {
    int v = part[g * 128 + t];
    buf[t] = v;
    __syncthreads();
    for (int off = 1; off < 128; off <<= 1) {
      int u = (t >= off) ? buf[t - off] : 0;
      __syncthreads();
      buf[t] += u;
      __syncthreads();
    }
    part[g * 128 + t] = buf[t] - v;
    __syncthreads();
  }
}
// phase c: in-block exclusive scan + base -> offs. grid (NB79, 3)
__global__ void k_scan_c(const int* __restrict__ cnt, const int* __restrict__ part,
                         int* __restrict__ offs) {
  __shared__ int buf[256];
  int g = blockIdx.y, b = blockIdx.x, t = threadIdx.x;
  int i = b * 256 + t;
  int v = (i < NN) ? cnt[g * NN + i] : 0;
  buf[t] = v;
  __syncthreads();
  for (int off = 1; off < 256; off <<= 1) {
    int u = (t >= off) ? buf[t - off] : 0;
    __syncthreads();
    buf[t] += u;
    __syncthreads();
  }
  int base = part[g * 128 + b];
  int excl = base + buf[t] - v;
  if (i < NN) offs[g * (NN + 1) + i] = excl;
  if (i == NN - 1) offs[g * (NN + 1) + NN] = excl + v;
}
__global__ void k_fill_csr3(EJobs js, const float* __restrict__ dinv,
                            const int* __restrict__ offs, int* cur,
                            int* csrc, float* cw) {
  int g = blockIdx.y;
  int e = blockIdx.x * blockDim.x + threadIdx.x;
  if (e >= NE) return;
  int s = js.ei[g][e], d = js.ei[g][NE + e];
  float w = js.ew[g][e];
  int pos = offs[g * (NN + 1) + d] + atomicAdd(&cur[g * NN + d], 1);
  csrc[g * NE + pos] = s;
  cw[g * NE + pos] = dinv[g * NN + s] * w * dinv[g * NN + d];
}

// ---------------- GEMM (bf16 MFMA, 128x128 tile, BK=64, XOR-swizzled LDS) ----------------

__device__ __forceinline__ void gload_lds16(const void* g, void* l) {
  __builtin_amdgcn_global_load_lds((const AS1 void*)g, (AS3 void*)l, 16, 0, 0);
}

struct GemmJob {
  const u16* A; const u16* BT; const float* bias;
  float* outF; u16* outB;
  int lda, ldb, K;
};

template <int NJ>
__global__ __launch_bounds__(256) void k_gemm(GemmJob j0, GemmJob j1, GemmJob j2,
                                              int M, int ldf, int ldob, long obOff) {
  GemmJob jb = j0;
  if (NJ > 1 && blockIdx.z == 1) jb = j1;
  if (NJ > 2 && blockIdx.z == 2) jb = j2;
  __shared__ u16 lA[8192];
  __shared__ u16 lB[8192];
  const int tid = threadIdx.x;
  const int l = tid & 63;
  const int w = tid >> 6;
  const int wr = w >> 1, wc = w & 1;
  const int n0 = blockIdx.x * 128, m0 = blockIdx.y * 128;

  f32x4 acc[4][4];
  const f32x4 z = {0.f, 0.f, 0.f, 0.f};
#pragma unroll
  for (int i = 0; i < 4; i++)
#pragma unroll
    for (int j = 0; j < 4; j++) acc[i][j] = z;

  // staging: slot s = q*256+tid; layout: kc2=s&3, r=(s>>2)&127, klh=s>>9
  // global chunk k-offset = klh*32 + ((kc2 ^ ((r>>2)&3))<<3  (XOR swizzle)
  const u16* gA[4]; const u16* gB[4];
  u16* lAq[4]; u16* lBq[4];
#pragma unroll
  for (int q = 0; q < 4; q++) {
    int s = q * 256 + tid;
    int kc2 = s & 3, r = (s >> 2) & 127, klh = s >> 9;
    int koff = klh * 32 + ((kc2 ^ ((r >> 2) & 3)) << 3);
    int ra = m0 + r; if (ra > M - 1) ra = M - 1;
    gA[q] = jb.A + (size_t)ra * jb.lda + koff;
    gB[q] = jb.BT + (size_t)(n0 + r) * jb.ldb + koff;
    lAq[q] = lA + (size_t)(q * 256 + w * 64) * 8;  // wave-uniform base
    lBq[q] = lB + (size_t)(q * 256 + w * 64) * 8;
  }

  const int fr = l & 15, qd = l >> 4;
  const int swz = ((qd ^ ((fr >> 2) & 3)) << 3);
  // LDS read elem offset for (row, kk): kk*4096 + row*32 + swz
  const int aro[4] = {(wr * 64 + 0 * 16 + fr) * 32 + swz, (wr * 64 + 1 * 16 + fr) * 32 + swz,
                      (wr * 64 + 2 * 16 + fr) * 32 + swz, (wr * 64 + 3 * 16 + fr) * 32 + swz};
  const int bro[4] = {(wc * 64 + 0 * 16 + fr) * 32 + swz, (wc * 64 + 1 * 16 + fr) * 32 + swz,
                      (wc * 64 + 2 * 16 + fr) * 32 + swz, (wc * 64 + 3 * 16 + fr) * 32 + swz};

  const int K = jb.K;
  for (int kt = 0; kt < K; kt += 64) {
    __syncthreads();
#pragma unroll
    for (int q = 0; q < 4; q++) {
      gload_lds16(gA[q] + kt, lAq[q]);
      gload_lds16(gB[q] + kt, lBq[q]);
    }
    __syncthreads();
#pragma unroll
    for (int kk = 0; kk < 2; kk++) {
      short8 af[4], bf[4];
#pragma unroll
      for (int t = 0; t < 4; t++) {
        af[t] = *(const short8*)(lA + kk * 4096 + aro[t]);
        bf[t] = *(const short8*)(lB + kk * 4096 + bro[t]);
      }
#pragma unroll
      for (int i = 0; i < 4; i++)
#pragma unroll
        for (int j = 0; j < 4; j++)
          acc[i][j] = __builtin_amdgcn_mfma_f32_16x16x32_bf16(af[i], bf[j], acc[i][j], 0, 0, 0);
    }
  }

#pragma unroll
  for (int i = 0; i < 4; i++) {
#pragma unroll
    for (int r = 0; r < 4; r++) {
      int m = m0 + wr * 64 + i * 16 + qd * 4 + r;
      if (m < M) {
#pragma unroll
        for (int j = 0; j < 4; j++) {
          int n = n0 + wc * 64 + j * 16 + fr;
          float v = acc[i][j][r];
          if (jb.bias) v += jb.bias[n];
          if (jb.outF) jb.outF[(size_t)m * ldf + n] = v;
          if (jb.outB) jb.outB[(size_t)m * ldob + obOff + n] = f2bf(v);
        }
      }
    }
  }
}

// ---------------- aggregation (pull, wave per node) ----------------

struct AggJob {
  const u16* H;
  const int* offs; const int* csrc; const float* cw; const float* dinv;
  const float* bias;
  float* outF; u16* outB;
  long obOff; int colOff;
};

template <int CPL>   // cols per lane: 8 (512 cols) or 4 (256 cols)
__global__ void k_agg(AggJob j0, AggJob j1, AggJob j2, int ldh, int ldf, int ldob,
                      int relu) {
  AggJob jb = j0;
  if (blockIdx.y == 1) jb = j1;
  if (blockIdx.y == 2) jb = j2;
  int wid = blockIdx.x * (blockDim.x >> 6) + (threadIdx.x >> 6);
  if (wid >= NN) return;
  int l = threadIdx.x & 63;
  const u16* hbase = jb.H + jb.colOff + (size_t)l * CPL;
  float acc[CPL], f0[CPL], f1[CPL];
  float dv = jb.dinv[wid];
  float sw = dv * dv;   // self-loop norm
  if (CPL == 8) ld_bf16x8(hbase + (size_t)wid * ldh, f0);
  else          ld_bf16x4(hbase + (size_t)wid * ldh, f0);
#pragma unroll
  for (int j = 0; j < CPL; j++) acc[j] = f0[j] * sw;
  int e = jb.offs[wid], e1 = jb.offs[wid + 1];
  for (; e + 2 <= e1; e += 2) {
    int s0 = jb.csrc[e], s1 = jb.csrc[e + 1];
    float w0 = jb.cw[e], w1 = jb.cw[e + 1];
    if (CPL == 8) { ld_bf16x8(hbase + (size_t)s0 * ldh, f0); ld_bf16x8(hbase + (size_t)s1 * ldh, f1); }
    else          { ld_bf16x4(hbase + (size_t)s0 * ldh, f0); ld_bf16x4(hbase + (size_t)s1 * ldh, f1); }
#pragma unroll
    for (int j = 0; j < CPL; j++) acc[j] += f0[j] * w0;
#pragma unroll
    for (int j = 0; j < CPL; j++) acc[j] += f1[j] * w1;
  }
  if (e < e1) {
    int s0 = jb.csrc[e];
    float w0 = jb.cw[e];
    if (CPL == 8) ld_bf16x8(hbase + (size_t)s0 * ldh, f0);
    else          ld_bf16x4(hbase + (size_t)s0 * ldh, f0);
#pragma unroll
    for (int j = 0; j < CPL; j++) acc[j] += f0[j] * w0;
  }
  const float* bp = jb.bias + l * CPL;
#pragma unroll
  for (int j = 0; j < CPL; j++) {
    float v = acc[j] + bp[j];
    if (relu) v = v > 0.f ? v : 0.f;
    acc[j] = v;
  }
  if (jb.outF) {
    float* q = jb.outF + (size_t)wid * ldf + l * CPL;
#pragma unroll
    for (int j = 0; j < CPL; j++) q[j] = acc[j];
  }
  if (jb.outB) {
    u16* q = jb.outB + (size_t)wid * ldob + jb.obOff + l * CPL;
#pragma unroll
    for (int j = 0; j < CPL; j++) q[j] = f2bf(acc[j]);
  }
}

// ---------------- launch ----------------

extern "C" void kernel_launch(void* const* d_in, const int* in_sizes, int n_in,
                              void* d_out, int out_size, void* d_ws, size_t ws_size,
                              hipStream_t stream) {
  (void)in_sizes; (void)n_in; (void)out_size; (void)ws_size;
  const float* x_RNA = (const float*)d_in[0];
  const float* x_ADT = (const float*)d_in[1];
  EJobs ej;
  ej.ei[0] = (const int*)d_in[2]; ej.ew[0] = (const float*)d_in[3];
  ej.ei[1] = (const int*)d_in[4]; ej.ew[1] = (const float*)d_in[5];
  ej.ei[2] = (const int*)d_in[6]; ej.ew[2] = (const float*)d_in[7];
  const float* W_rna1 = (const float*)d_in[8];  const float* b_rna1 = (const float*)d_in[9];
  const float* W_rna2 = (const float*)d_in[10]; const float* b_rna2 = (const float*)d_in[11];
  const float* W_p3   = (const float*)d_in[12]; const float* b_p3   = (const float*)d_in[13];
  const float* W_sim  = (const float*)d_in[14]; const float* b_sim  = (const float*)d_in[15];
  const float* W_dist = (const float*)d_in[16]; const float* b_dist = (const float*)d_in[17];
  const float* W_f1   = (const float*)d_in[18]; const float* b_f1   = (const float*)d_in[19];
  const float* W_f2   = (const float*)d_in[20]; const float* b_f2   = (const float*)d_in[21];
  float* out = (float*)d_out;

  // ---- workspace layout ----
  char* p = (char*)d_ws;
  auto alloc = [&](size_t bytes) {
    char* r = p;
    p += (bytes + 255) & ~(size_t)255;
    return r;
  };
  u16* WcT  = (u16*)alloc((size_t)1024 * KX * 2);
  u16* WsT  = (u16*)alloc((size_t)OUTC * HID * 2);
  u16* WdT  = (u16*)alloc((size_t)OUTC * HID * 2);
  u16* Wf1T = (u16*)alloc((size_t)OUTC * HID * 2);
  u16* Wf2T = (u16*)alloc((size_t)OUTC * HID * 2);
  u16* Wp3T = (u16*)alloc((size_t)OUTC * KQ * 2);
  u16* ADTb = (u16*)alloc((size_t)NN * KQ * 2);
  u16* H1   = (u16*)alloc((size_t)NN * 1024 * 2);  // later: H2s|H2d|H2p
  u16* B2   = (u16*)alloc((size_t)NN * 1024 * 2);  // XS|XD, later XSD|FP
  float* deg = (float*)alloc((size_t)3 * NN * 4);
  int* cnt   = (int*)alloc((size_t)3 * NN * 4);
  int* offs  = (int*)alloc((size_t)3 * (NN + 1) * 4);
  int* cur   = (int*)alloc((size_t)3 * NN * 4);
  int* csrc  = (int*)alloc((size_t)3 * NE * 4);
  float* cwn = (float*)alloc((size_t)3 * NE * 4);
  int* part  = (int*)alloc(3 * 128 * 4);

  u16* Xb = (u16*)d_out;   // bf16 x_RNA scratch: dead before first f32 output write
  u16* XS  = B2;
  u16* XD  = B2 + (size_t)NN * 512;
  u16* XSD = B2;
  u16* FP  = B2 + (size_t)NN * 512;
  u16* H2s = H1;
  u16* H2d = H1 + (size_t)NN * 256;
  u16* H2p = H1 + (size_t)NN * 512;

  const int T = 256;
  // casts
  k_cast_pad<<<(NN * (KX / 8) + T - 1) / T, T, 0, stream>>>(x_RNA, Xb, NN, INC, KX);
  k_cast_pad<<<(NN * (KQ / 8) + T - 1) / T, T, 0, stream>>>(x_ADT, ADTb, NN, QA, KQ);
  k_wcT<<<dim3(32, 16), 256, 0, stream>>>(W_rna1, W_rna2, WcT);
  W5 w5;
  w5.W[0] = W_sim;  w5.o[0] = WsT;  w5.Kin[0] = HID; w5.Kpad[0] = HID; w5.Nw[0] = OUTC;
  w5.W[1] = W_dist; w5.o[1] = WdT;  w5.Kin[1] = HID; w5.Kpad[1] = HID; w5.Nw[1] = OUTC;
  w5.W[2] = W_f1;   w5.o[2] = Wf1T; w5.Kin[2] = HID; w5.Kpad[2] = HID; w5.Nw[2] = OUTC;
  w5.W[3] = W_f2;   w5.o[3] = Wf2T; w5.Kin[3] = HID; w5.Kpad[3] = HID; w5.Nw[3] = OUTC;
  w5.W[4] = W_p3;   w5.o[4] = Wp3T; w5.Kin[4] = QA;  w5.Kpad[4] = KQ;  w5.Nw[4] = OUTC;
  k_wT5<<<dim3(64, 5), T, 0, stream>>>(w5);
  // CSR (all 3 graphs per launch)
  k_init_csr<<<(3 * NN + T - 1) / T, T, 0, stream>>>(deg, cnt, cur);
  k_edge_count<<<dim3((NE + T - 1) / T, 3), T, 0, stream>>>(ej, deg, cnt);
  k_dinv<<<(3 * NN + T - 1) / T, T, 0, stream>>>(deg);
  k_scan_a<<<dim3(NB79, 3), 256, 0, stream>>>(cnt, part);
  k_scan_b<<<1, 128, 0, stream>>>(part);
  k_scan_c<<<dim3(NB79, 3), 256, 0, stream>>>(cnt, part, offs);
  k_fill_csr3<<<dim3((NE + T - 1) / T, 3), T, 0, stream>>>(ej, deg, offs, cur, csrc, cwn);

  GemmJob jz = {};
  // G1: H1 = Xb @ [W_rna1|W_rna2]
  GemmJob g1 = {Xb, WcT, nullptr, nullptr, H1, KX, KX, KX};
  k_gemm<1><<<dim3(8, 157, 1), 256, 0, stream>>>(g1, jz, jz, NN, 0, 1024, 0);
  // A1: XS = relu(agg_sim(H1[:,:512]) + b_rna1); XD likewise (dist)
  AggJob a0 = {H1, offs, csrc, cwn, deg, b_rna1, nullptr, XS, 0, 0};
  AggJob a1 = {H1, offs + (NN + 1), csrc + NE, cwn + NE, deg + NN, b_rna2, nullptr, XD, 0, 512};
  k_agg<8><<<dim3(NN / 4, 2), 256, 0, stream>>>(a0, a1, a1, 1024, 0, 512, 1);
  // G2 (3 jobs): H2s=XS@W_sim, H2d=XD@W_dist, H2p=ADTb@W_p3
  GemmJob g2a = {XS, WsT, nullptr, nullptr, H2s, HID, HID, HID};
  GemmJob g2b = {XD, WdT, nullptr, nullptr, H2d, HID, HID, HID};
  GemmJob g2c = {ADTb, Wp3T, nullptr, nullptr, H2p, KQ, KQ, KQ};
  k_gemm<3><<<dim3(2, 157, 3), 256, 0, stream>>>(g2a, g2b, g2c, NN, 0, 256, 0);
  // A2 (3 jobs): x_sim, x_dist, pro -> f32 outputs + bf16 copies for fusion
  AggJob b0 = {H2s, offs, csrc, cwn, deg, b_sim, out, XSD, 0, 0};
  AggJob b1 = {H2d, offs + (NN + 1), csrc + NE, cwn + NE, deg + NN, b_dist,
               out + OUTSZ, XSD, 256, 0};
  AggJob b2 = {H2p, offs + 2 * (NN + 1), csrc + 2 * NE, cwn + 2 * NE, deg + 2 * NN, b_p3,
               out + 4 * OUTSZ, FP, 256, 0};
  k_agg<4><<<dim3(NN / 4, 3), 256, 0, stream>>>(b0, b1, b2, 256, 256, 512, 0);
  // G3: fused = XSD @ W_f1 + b_f1
  GemmJob g3 = {XSD, Wf1T, b_f1, out + 2 * OUTSZ, FP, HID, HID, HID};
  k_gemm<1><<<dim3(2, 157, 1), 256, 0, stream>>>(g3, jz, jz, NN, 256, 512, 0);
  // G4: fused_pro = FP @ W_f2 + b_f2
  GemmJob g4 = {FP, Wf2T, b_f2, out + 3 * OUTSZ, nullptr, HID, HID, HID};
  k_gemm<1><<<dim3(2, 157, 1), 256, 0, stream>>>(g4, jz, jz, NN, 256, 0, 0);
}

// Round 3
// 835.957 us; speedup vs baseline: 1.3492x; 1.0318x over previous
//
#include <hip/hip_runtime.h>

#define AS1 __attribute__((address_space(1)))
#define AS3 __attribute__((address_space(3)))

typedef __attribute__((ext_vector_type(8))) short short8;
typedef __attribute__((ext_vector_type(4))) float f32x4;
typedef unsigned int u32;
typedef unsigned short u16;

static constexpr int NN = 20000;
static constexpr int NE = 320000;
static constexpr int INC = 2000;
static constexpr int KX = 2048;
static constexpr int HID = 512;
static constexpr int OUTC = 256;
static constexpr int QA = 100;
static constexpr int KQ = 128;
static constexpr long OUTSZ = (long)NN * OUTC;
static constexpr int NB79 = (NN + 255) / 256;   // 79

__device__ __forceinline__ u16 f2bf(float f) {
  u32 u = __float_as_uint(f);
  u = (u + 0x7FFFu + ((u >> 16) & 1u)) >> 16;   // RNE
  return (u16)u;
}
__device__ __forceinline__ void ld_bf16x8(const u16* p, float* f) {
  uint4 r = *(const uint4*)p;
  f[0] = __uint_as_float(r.x << 16); f[1] = __uint_as_float(r.x & 0xFFFF0000u);
  f[2] = __uint_as_float(r.y << 16); f[3] = __uint_as_float(r.y & 0xFFFF0000u);
  f[4] = __uint_as_float(r.z << 16); f[5] = __uint_as_float(r.z & 0xFFFF0000u);
  f[6] = __uint_as_float(r.w << 16); f[7] = __uint_as_float(r.w & 0xFFFF0000u);
}
__device__ __forceinline__ void ld_bf16x4(const u16* p, float* f) {
  uint2 r = *(const uint2*)p;
  f[0] = __uint_as_float(r.x << 16); f[1] = __uint_as_float(r.x & 0xFFFF0000u);
  f[2] = __uint_as_float(r.y << 16); f[3] = __uint_as_float(r.y & 0xFFFF0000u);
}

// ---------------- fused prep kernel ----------------
// R0 [0,20000): x_RNA row cast->Xb ; R1 [20000,21250): x_ADT cast (16 rows/blk)
// R2 [21250,21522): 5 small-weight transposes ; R3 [21522,22034): WcT LDS transpose
// R4 [22034,22803): Wcat compose + bias2 ; R5 [22803,23038): CSR state init
struct Prep {
  const float *xR, *xA;
  const float *W1, *W2;                     // W_rna1, W_rna2
  const float *Ws0, *Ws1, *Ws2, *Ws3, *Ws4; // W_sim, W_dist, W_f1, W_f2, W_p3
  u16 *Wo0, *Wo1, *Wo2, *Wo3, *Wo4;
  const float *bf1, *bf2;
  u16 *Xb, *ADTb, *WcT, *WcatT;
  float *bias2;
  float *deg; int *cnt; int *cur;
};

__global__ __launch_bounds__(256) void k_prep(Prep P) {
  int b = blockIdx.x, t = threadIdx.x;
  if (b < 20000) {                       // ---- R0: x_RNA row cast
    int c8 = t << 3;
    u16 v[8];
    if (c8 + 8 <= INC) {
      const float4* p = (const float4*)(P.xR + (long)b * INC + c8);
      float4 a = p[0], c = p[1];
      v[0] = f2bf(a.x); v[1] = f2bf(a.y); v[2] = f2bf(a.z); v[3] = f2bf(a.w);
      v[4] = f2bf(c.x); v[5] = f2bf(c.y); v[6] = f2bf(c.z); v[7] = f2bf(c.w);
    } else {
#pragma unroll
      for (int j = 0; j < 8; j++) {
        int c = c8 + j;
        v[j] = (c < INC) ? f2bf(P.xR[(long)b * INC + c]) : (u16)0;
      }
    }
    *(uint4*)(P.Xb + (long)b * KX + c8) = *(const uint4*)v;
    return;
  }
  if (b < 21250) {                       // ---- R1: x_ADT cast, 16 rows/block
    int row = (b - 20000) * 16 + (t >> 4);
    int c8 = (t & 15) << 3;
    u16 v[8];
#pragma unroll
    for (int j = 0; j < 8; j++) {
      int c = c8 + j;
      v[j] = (c < QA) ? f2bf(P.xA[(long)row * QA + c]) : (u16)0;
    }
    *(uint4*)(P.ADTb + (long)row * KQ + c8) = *(const uint4*)v;
    return;
  }
  if (b < 21522) {                       // ---- R2: wT5
    int slot = (b - 21250) * 256 + t;
    const float* W; u16* o; int Kin, Kpad, within;
    if (slot < 65536) {
      int j = slot >> 14; within = slot & 16383;
      W = (j == 0) ? P.Ws0 : (j == 1) ? P.Ws1 : (j == 2) ? P.Ws2 : P.Ws3;
      o = (j == 0) ? P.Wo0 : (j == 1) ? P.Wo1 : (j == 2) ? P.Wo2 : P.Wo3;
      Kin = HID; Kpad = HID;
    } else {
      within = slot - 65536; W = P.Ws4; o = P.Wo4; Kin = QA; Kpad = KQ;
    }
    int kg = Kpad >> 3;
    int n = within / kg, k8 = (within % kg) << 3;
    u16 v[8];
#pragma unroll
    for (int j = 0; j < 8; j++) {
      int k = k8 + j;
      v[j] = (k < Kin) ? f2bf(W[(long)k * OUTC + n]) : (u16)0;
    }
    *(uint4*)(o + (long)n * Kpad + k8) = *(const uint4*)v;
    return;
  }
  if (b < 22034) {                       // ---- R3: WcT transpose
    __shared__ float tile[64][65];
    int bb = b - 21522;
    int kb = (bb & 31) * 64, nb = (bb >> 5) * 64;
    const float* W = (nb < HID) ? P.W1 : P.W2;
    int nb2 = nb & (HID - 1);
#pragma unroll
    for (int p = 0; p < 4; p++) {
      int idx = p * 256 + t;
      int r = idx >> 4, c4 = (idx & 15) << 2;
      int k = kb + r;
      float4 v = {0.f, 0.f, 0.f, 0.f};
      if (k < INC) v = *(const float4*)(W + (long)k * HID + nb2 + c4);
      tile[r][c4] = v.x; tile[r][c4 + 1] = v.y; tile[r][c4 + 2] = v.z; tile[r][c4 + 3] = v.w;
    }
    __syncthreads();
#pragma unroll
    for (int p = 0; p < 2; p++) {
      int idx = p * 256 + t;
      int n = idx >> 3, kg = (idx & 7) << 3;
      u16 v[8];
#pragma unroll
      for (int j = 0; j < 8; j++) v[j] = f2bf(tile[kg + j][n]);
      *(uint4*)(P.WcT + (long)(nb + n) * KX + kb + kg) = *(const uint4*)v;
    }
    return;
  }
  if (b < 22803) {                       // ---- R4: Wcat compose
    int k = b - 22034;                   // 0..768 (768 == bias block)
    int n = t;
    if (k < 512) {
      float s = 0.f;
      for (int j = 0; j < 256; j++) s += P.Ws2[k * OUTC + j] * P.Ws3[j * OUTC + n];
      P.WcatT[(long)n * 768 + k] = f2bf(s);
    } else if (k < 768) {
      P.WcatT[(long)n * 768 + k] = f2bf(P.Ws3[(256 + k - 512) * OUTC + n]);
    } else {
      float s = P.bf2[n];
      for (int j = 0; j < 256; j++) s += P.bf1[j] * P.Ws3[j * OUTC + n];
      P.bias2[n] = s;
    }
    return;
  }
  {                                      // ---- R5: CSR init
    int i = (b - 22803) * 256 + t;
    if (i < 3 * NN) { P.deg[i] = 1.0f; P.cnt[i] = 0; P.cur[i] = 0; }
  }
}

// ---------------- CSR build ----------------

struct EJobs { const int* ei[3]; const float* ew[3]; };

__global__ void k_edge_count(EJobs js, float* deg, int* cnt) {
  int g = blockIdx.y;
  int e = blockIdx.x * blockDim.x + threadIdx.x;
  if (e >= NE) return;
  int dst = js.ei[g][NE + e];
  atomicAdd(&deg[g * NN + dst], js.ew[g][e]);
  atomicAdd(&cnt[g * NN + dst], 1);
}
// per-block sums + dinv. grid (NB79, 3)
__global__ void k_scan_a(const int* __restrict__ cnt, int* __restrict__ part,
                         float* deg) {
  __shared__ int buf[256];
  int g = blockIdx.y, b = blockIdx.x, t = threadIdx.x;
  int i = b * 256 + t;
  if (i < NN) deg[g * NN + i] = rsqrtf(deg[g * NN + i]);   // deg >= 1 (self loop)
  int v = (i < NN) ? cnt[g * NN + i] : 0;
  buf[t] = v;
  __syncthreads();
  for (int off = 128; off > 0; off >>= 1) {
    if (t < off) buf[t] += buf[t + off];
    __syncthreads();
  }
  if (t == 0) part[g * 128 + b] = buf[0];
}
__global__ void k_scan_b(int* part) {
  __shared__ int buf[128];
  int t = threadIdx.x;
  for (int g = 0; g < 3; g++) {
    int v = part[g * 128 + t];
    buf[t] = v;
    __syncthreads();
    for (int off = 1; off < 128; off <<= 1) {
      int u = (t >= off) ? buf[t - off] : 0;
      __syncthreads();
      buf[t] += u;
      __syncthreads();
    }
    part[g * 128 + t] = buf[t] - v;
    __syncthreads();
  }
}
__global__ void k_scan_c(const int* __restrict__ cnt, const int* __restrict__ part,
                         int* __restrict__ offs) {
  __shared__ int buf[256];
  int g = blockIdx.y, b = blockIdx.x, t = threadIdx.x;
  int i = b * 256 + t;
  int v = (i < NN) ? cnt[g * NN + i] : 0;
  buf[t] = v;
  __syncthreads();
  for (int off = 1; off < 256; off <<= 1) {
    int u = (t >= off) ? buf[t - off] : 0;
    __syncthreads();
    buf[t] += u;
    __syncthreads();
  }
  int base = part[g * 128 + b];
  int excl = base + buf[t] - v;
  if (i < NN) offs[g * (NN + 1) + i] = excl;
  if (i == NN - 1) offs[g * (NN + 1) + NN] = excl + v;
}
__global__ void k_fill_csr3(EJobs js, const float* __restrict__ dinv,
                            const int* __restrict__ offs, int* cur,
                            int* csrc, float* cw) {
  int g = blockIdx.y;
  int e = blockIdx.x * blockDim.x + threadIdx.x;
  if (e >= NE) return;
  int s = js.ei[g][e], d = js.ei[g][NE + e];
  float w = js.ew[g][e];
  int pos = offs[g * (NN + 1) + d] + atomicAdd(&cur[g * NN + d], 1);
  csrc[g * NE + pos] = s;
  cw[g * NE + pos] = dinv[g * NN + s] * w * dinv[g * NN + d];
}

// ------- GEMM: bf16 MFMA 128x128 tile, BK=32, double-buffered LDS, 1 barrier/iter -------

__device__ __forceinline__ void gload_lds16(const void* g, void* l) {
  __builtin_amdgcn_global_load_lds((const AS1 void*)g, (AS3 void*)l, 16, 0, 0);
}

struct GemmJob {
  const u16* A; const u16* BT; const float* bias;
  float* outF; u16* outB;
  int lda, ldb, K;
};

template <int NJ>
__global__ __launch_bounds__(256) void k_gemm(GemmJob j0, GemmJob j1, GemmJob j2,
                                              int M, int ldf, int ldob, long obOff,
                                              int xcdswz) {
  GemmJob jb = j0;
  if (NJ > 1 && blockIdx.z == 1) jb = j1;
  if (NJ > 2 && blockIdx.z == 2) jb = j2;
  int m_i, n_i;
  if (xcdswz) {
    // grid (8, 160): XCD = linear%8 owns an m-stripe; n cycles fastest per XCD.
    int L = blockIdx.x + (blockIdx.y << 3);
    int xcd = L & 7, j = L >> 3;
    n_i = j & 7;
    m_i = ((j >> 3) << 3) + xcd;
    if (m_i >= 157) return;
  } else {
    n_i = blockIdx.x; m_i = blockIdx.y;
  }
  const int m0 = m_i * 128, n0 = n_i * 128;

  __shared__ u16 lA[2][4096];
  __shared__ u16 lB[2][4096];
  const int tid = threadIdx.x;
  const int l = tid & 63;
  const int w = tid >> 6;
  const int wr = w >> 1, wc = w & 1;

  f32x4 acc[4][4];
  const f32x4 z = {0.f, 0.f, 0.f, 0.f};
#pragma unroll
  for (int i = 0; i < 4; i++)
#pragma unroll
    for (int j = 0; j < 4; j++) acc[i][j] = z;

  // staging: slot s = q*256+tid -> tile row r=s>>2, k-chunk kc=s&3 (8 elems)
  const u16* gA[2]; const u16* gB[2];
  int ldst[2];
#pragma unroll
  for (int q = 0; q < 2; q++) {
    int s = q * 256 + tid;
    int r = s >> 2, kc = s & 3;
    int ra = m0 + r; if (ra > M - 1) ra = M - 1;
    gA[q] = jb.A + (size_t)ra * jb.lda + kc * 8;
    gB[q] = jb.BT + (size_t)(n0 + r) * jb.ldb + kc * 8;
    ldst[q] = (q * 256 + w * 64) * 8;    // wave-uniform LDS base (elems)
  }

  const int fr = l & 15, qd = l >> 4;
  const int aro[4] = {(wr * 64 + 0 * 16 + fr) * 32 + qd * 8, (wr * 64 + 1 * 16 + fr) * 32 + qd * 8,
                      (wr * 64 + 2 * 16 + fr) * 32 + qd * 8, (wr * 64 + 3 * 16 + fr) * 32 + qd * 8};
  const int bro[4] = {(wc * 64 + 0 * 16 + fr) * 32 + qd * 8, (wc * 64 + 1 * 16 + fr) * 32 + qd * 8,
                      (wc * 64 + 2 * 16 + fr) * 32 + qd * 8, (wc * 64 + 3 * 16 + fr) * 32 + qd * 8};

  const int nit = jb.K >> 5;
  // prologue: stage iter 0 into buf 0
#pragma unroll
  for (int q = 0; q < 2; q++) {
    gload_lds16(gA[q], &lA[0][0] + ldst[q]);
    gload_lds16(gB[q], &lB[0][0] + ldst[q]);
  }
  for (int i = 0; i < nit; i++) {
    __syncthreads();                       // drains stage(i); protects buffers
    if (i + 1 < nit) {
      int nb = (i + 1) & 1, kt = (i + 1) * 32;
#pragma unroll
      for (int q = 0; q < 2; q++) {
        gload_lds16(gA[q] + kt, &lA[nb][0] + ldst[q]);
        gload_lds16(gB[q] + kt, &lB[nb][0] + ldst[q]);
      }
    }
    const u16* la = &lA[i & 1][0];
    const u16* lb = &lB[i & 1][0];
    short8 af[4], bf[4];
#pragma unroll
    for (int t = 0; t < 4; t++) {
      af[t] = *(const short8*)(la + aro[t]);
      bf[t] = *(const short8*)(lb + bro[t]);
    }
#pragma unroll
    for (int i2 = 0; i2 < 4; i2++)
#pragma unroll
      for (int j = 0; j < 4; j++)
        acc[i2][j] = __builtin_amdgcn_mfma_f32_16x16x32_bf16(af[i2], bf[j], acc[i2][j], 0, 0, 0);
  }

#pragma unroll
  for (int i = 0; i < 4; i++) {
#pragma unroll
    for (int r = 0; r < 4; r++) {
      int m = m0 + wr * 64 + i * 16 + qd * 4 + r;
      if (m < M) {
#pragma unroll
        for (int j = 0; j < 4; j++) {
          int n = n0 + wc * 64 + j * 16 + fr;
          float v = acc[i][j][r];
          if (jb.bias) v += jb.bias[n];
          if (jb.outF) jb.outF[(size_t)m * ldf + n] = v;
          if (jb.outB) jb.outB[(size_t)m * ldob + obOff + n] = f2bf(v);
        }
      }
    }
  }
}

// ---------------- aggregation (pull, wave per node) ----------------

struct AggJob {
  const u16* H;
  const int* offs; const int* csrc; const float* cw; const float* dinv;
  const float* bias;
  float* outF; u16* outB;
  long obOff; int colOff;
};

template <int CPL>
__global__ void k_agg(AggJob j0, AggJob j1, AggJob j2, int ldh, int ldf, int ldob,
                      int relu) {
  AggJob jb = j0;
  if (blockIdx.y == 1) jb = j1;
  if (blockIdx.y == 2) jb = j2;
  int wid = blockIdx.x * (blockDim.x >> 6) + (threadIdx.x >> 6);
  if (wid >= NN) return;
  int l = threadIdx.x & 63;
  const u16* hbase = jb.H + jb.colOff + (size_t)l * CPL;
  float acc[CPL], f0[CPL], f1[CPL];
  float dv = jb.dinv[wid];
  float sw = dv * dv;
  if (CPL == 8) ld_bf16x8(hbase + (size_t)wid * ldh, f0);
  else          ld_bf16x4(hbase + (size_t)wid * ldh, f0);
#pragma unroll
  for (int j = 0; j < CPL; j++) acc[j] = f0[j] * sw;
  int e = jb.offs[wid], e1 = jb.offs[wid + 1];
  for (; e + 2 <= e1; e += 2) {
    int s0 = jb.csrc[e], s1 = jb.csrc[e + 1];
    float w0 = jb.cw[e], w1 = jb.cw[e + 1];
    if (CPL == 8) { ld_bf16x8(hbase + (size_t)s0 * ldh, f0); ld_bf16x8(hbase + (size_t)s1 * ldh, f1); }
    else          { ld_bf16x4(hbase + (size_t)s0 * ldh, f0); ld_bf16x4(hbase + (size_t)s1 * ldh, f1); }
#pragma unroll
    for (int j = 0; j < CPL; j++) acc[j] += f0[j] * w0;
#pragma unroll
    for (int j = 0; j < CPL; j++) acc[j] += f1[j] * w1;
  }
  if (e < e1) {
    int s0 = jb.csrc[e];
    float w0 = jb.cw[e];
    if (CPL == 8) ld_bf16x8(hbase + (size_t)s0 * ldh, f0);
    else          ld_bf16x4(hbase + (size_t)s0 * ldh, f0);
#pragma unroll
    for (int j = 0; j < CPL; j++) acc[j] += f0[j] * w0;
  }
  const float* bp = jb.bias + l * CPL;
#pragma unroll
  for (int j = 0; j < CPL; j++) {
    float v = acc[j] + bp[j];
    if (relu) v = v > 0.f ? v : 0.f;
    acc[j] = v;
  }
  if (jb.outF) {
    float* q = jb.outF + (size_t)wid * ldf + l * CPL;
#pragma unroll
    for (int j = 0; j < CPL; j++) q[j] = acc[j];
  }
  if (jb.outB) {
    u16* q = jb.outB + (size_t)wid * ldob + jb.obOff + l * CPL;
#pragma unroll
    for (int j = 0; j < CPL; j++) q[j] = f2bf(acc[j]);
  }
}

// ---------------- launch ----------------

extern "C" void kernel_launch(void* const* d_in, const int* in_sizes, int n_in,
                              void* d_out, int out_size, void* d_ws, size_t ws_size,
                              hipStream_t stream) {
  (void)in_sizes; (void)n_in; (void)out_size; (void)ws_size;
  const float* x_RNA = (const float*)d_in[0];
  const float* x_ADT = (const float*)d_in[1];
  EJobs ej;
  ej.ei[0] = (const int*)d_in[2]; ej.ew[0] = (const float*)d_in[3];
  ej.ei[1] = (const int*)d_in[4]; ej.ew[1] = (const float*)d_in[5];
  ej.ei[2] = (const int*)d_in[6]; ej.ew[2] = (const float*)d_in[7];
  const float* W_rna1 = (const float*)d_in[8];  const float* b_rna1 = (const float*)d_in[9];
  const float* W_rna2 = (const float*)d_in[10]; const float* b_rna2 = (const float*)d_in[11];
  const float* W_p3   = (const float*)d_in[12]; const float* b_p3   = (const float*)d_in[13];
  const float* W_sim  = (const float*)d_in[14]; const float* b_sim  = (const float*)d_in[15];
  const float* W_dist = (const float*)d_in[16]; const float* b_dist = (const float*)d_in[17];
  const float* W_f1   = (const float*)d_in[18]; const float* b_f1   = (const float*)d_in[19];
  const float* W_f2   = (const float*)d_in[20]; const float* b_f2   = (const float*)d_in[21];
  float* out = (float*)d_out;

  char* p = (char*)d_ws;
  auto alloc = [&](size_t bytes) {
    char* r = p;
    p += (bytes + 255) & ~(size_t)255;
    return r;
  };
  u16* WcT   = (u16*)alloc((size_t)1024 * KX * 2);
  u16* WsT   = (u16*)alloc((size_t)OUTC * HID * 2);
  u16* WdT   = (u16*)alloc((size_t)OUTC * HID * 2);
  u16* Wf1T  = (u16*)alloc((size_t)OUTC * HID * 2);
  u16* Wp3T  = (u16*)alloc((size_t)OUTC * KQ * 2);
  u16* WcatT = (u16*)alloc((size_t)OUTC * 768 * 2);
  float* bias2 = (float*)alloc(OUTC * 4);
  u16* ADTb = (u16*)alloc((size_t)NN * KQ * 2);
  u16* H1   = (u16*)alloc((size_t)NN * 1024 * 2);  // later: H2s|H2d|H2p
  u16* B2   = (u16*)alloc((size_t)NN * 1024 * 2);  // XS|XD, later XSDP
  float* deg = (float*)alloc((size_t)3 * NN * 4);
  int* cnt   = (int*)alloc((size_t)3 * NN * 4);
  int* offs  = (int*)alloc((size_t)3 * (NN + 1) * 4);
  int* cur   = (int*)alloc((size_t)3 * NN * 4);
  int* csrc  = (int*)alloc((size_t)3 * NE * 4);
  float* cwn = (float*)alloc((size_t)3 * NE * 4);
  int* part  = (int*)alloc(3 * 128 * 4);

  u16* Xb   = (u16*)d_out;   // bf16 x_RNA scratch: dead before first f32 output write
  u16* XS   = B2;
  u16* XD   = B2 + (size_t)NN * 512;
  u16* XSDP = B2;            // [NN, 768] = x_sim | x_dist | pro (bf16), after A2
  u16* H2s  = H1;
  u16* H2d  = H1 + (size_t)NN * 256;
  u16* H2p  = H1 + (size_t)NN * 512;

  const int T = 256;
  Prep P;
  P.xR = x_RNA; P.xA = x_ADT; P.W1 = W_rna1; P.W2 = W_rna2;
  P.Ws0 = W_sim; P.Ws1 = W_dist; P.Ws2 = W_f1; P.Ws3 = W_f2; P.Ws4 = W_p3;
  P.Wo0 = WsT; P.Wo1 = WdT; P.Wo2 = Wf1T; P.Wo3 = nullptr; P.Wo4 = Wp3T;
  P.bf1 = b_f1; P.bf2 = b_f2;
  P.Xb = Xb; P.ADTb = ADTb; P.WcT = WcT; P.WcatT = WcatT; P.bias2 = bias2;
  P.deg = deg; P.cnt = cnt; P.cur = cur;
  // R2 job 3 (W_f2) is not transposed standalone anymore; reuse slot for Wf1T pad safety:
  P.Wo3 = Wf1T;   // harmless overwrite with same layout? NO -> give it scratch:
  P.Wo3 = (u16*)(cwn);  // dead scratch until k_fill_csr3; wT5 finishes in k_prep before it
  k_prep<<<23038, T, 0, stream>>>(P);

  k_edge_count<<<dim3((NE + T - 1) / T, 3), T, 0, stream>>>(ej, deg, cnt);
  k_scan_a<<<dim3(NB79, 3), 256, 0, stream>>>(cnt, part, deg);
  k_scan_b<<<1, 128, 0, stream>>>(part);
  k_scan_c<<<dim3(NB79, 3), 256, 0, stream>>>(cnt, part, offs);
  k_fill_csr3<<<dim3((NE + T - 1) / T, 3), T, 0, stream>>>(ej, deg, offs, cur, csrc, cwn);

  GemmJob jz = {};
  // G1: H1 = Xb @ [W_rna1|W_rna2]^T (XCD-swizzled grid)
  GemmJob g1 = {Xb, WcT, nullptr, nullptr, H1, KX, KX, KX};
  k_gemm<1><<<dim3(8, 160, 1), 256, 0, stream>>>(g1, jz, jz, NN, 0, 1024, 0, 1);
  // A1: XS = relu(agg_sim(H1[:,:512]) + b_rna1); XD likewise (dist)
  AggJob a0 = {H1, offs, csrc, cwn, deg, b_rna1, nullptr, XS, 0, 0};
  AggJob a1 = {H1, offs + (NN + 1), csrc + NE, cwn + NE, deg + NN, b_rna2, nullptr, XD, 0, 512};
  k_agg<8><<<dim3(NN / 4, 2), 256, 0, stream>>>(a0, a1, a1, 1024, 0, 512, 1);
  // G2: H2s=XS@W_sim, H2d=XD@W_dist, H2p=ADTb@W_p3
  GemmJob g2a = {XS, WsT, nullptr, nullptr, H2s, HID, HID, HID};
  GemmJob g2b = {XD, WdT, nullptr, nullptr, H2d, HID, HID, HID};
  GemmJob g2c = {ADTb, Wp3T, nullptr, nullptr, H2p, KQ, KQ, KQ};
  k_gemm<3><<<dim3(2, 157, 3), 256, 0, stream>>>(g2a, g2b, g2c, NN, 0, 256, 0, 0);
  // A2: x_sim, x_dist, pro -> f32 outputs + bf16 into XSDP
  AggJob b0 = {H2s, offs, csrc, cwn, deg, b_sim, out, XSDP, 0, 0};
  AggJob b1 = {H2d, offs + (NN + 1), csrc + NE, cwn + NE, deg + NN, b_dist,
               out + OUTSZ, XSDP, 256, 0};
  AggJob b2 = {H2p, offs + 2 * (NN + 1), csrc + 2 * NE, cwn + 2 * NE, deg + 2 * NN, b_p3,
               out + 4 * OUTSZ, XSDP, 512, 0};
  k_agg<4><<<dim3(NN / 4, 3), 256, 0, stream>>>(b0, b1, b2, 256, 256, 768, 0);
  // G5 (2 jobs): fused = XSDP[:,:512]@W_f1 + b_f1 ; fused_pro = XSDP@Wcat + bias2
  GemmJob g5a = {XSDP, Wf1T, b_f1, out + 2 * OUTSZ, nullptr, 768, 512, 512};
  GemmJob g5b = {XSDP, WcatT, bias2, out + 3 * OUTSZ, nullptr, 768, 768, 768};
  k_gemm<2><<<dim3(2, 157, 2), 256, 0, stream>>>(g5a, g5b, jz, NN, 256, 0, 0, 0);
}